// Round 1
// baseline (2898.169 us; speedup 1.0000x reference)
//
#include <hip/hip_runtime.h>
#include <stdint.h>

#define T_TOK 4096
#define DMODEL 2048
#define HDIM 8192
#define NEXP 8
#define CAP 2048   // 2 * ceil(2*4096/8)

typedef unsigned short u16;
typedef __attribute__((ext_vector_type(8))) short short8;
typedef __attribute__((ext_vector_type(4))) float f32x4;

__device__ __forceinline__ u16 f2bf(float f) {
  unsigned int u = __builtin_bit_cast(unsigned int, f);
  u += 0x7fffu + ((u >> 16) & 1u);          // RNE (inputs finite)
  return (u16)(u >> 16);
}
__device__ __forceinline__ float bf2f(u16 h) {
  return __builtin_bit_cast(float, ((unsigned int)h) << 16);
}

// ---------------------------------------------------------------------------
// 1. Routing: logits = x @ wg, softmax(8), top-2, partial me/ce sums.
//    Grid: 64 blocks x 256 thr. One wave per token, 16 tokens per wave.
// ---------------------------------------------------------------------------
__global__ __launch_bounds__(256) void routing_k(
    const float* __restrict__ x, const float* __restrict__ wg,
    int* __restrict__ idx0, int* __restrict__ idx1,
    float* __restrict__ g0, float* __restrict__ g1,
    float* __restrict__ me_part, int* __restrict__ ce_part) {
  __shared__ float sme[4][8];
  __shared__ int   sce[4][8];
  const int wave = threadIdx.x >> 6, lane = threadIdx.x & 63;
  float meAcc[8] = {0,0,0,0,0,0,0,0};
  int   ceAcc[8] = {0,0,0,0,0,0,0,0};
  for (int ti = 0; ti < 16; ++ti) {
    const int t = blockIdx.x * 64 + wave * 16 + ti;
    float acc[8] = {0,0,0,0,0,0,0,0};
    for (int i = 0; i < 32; ++i) {
      const int d = i * 64 + lane;
      const float xv = x[(size_t)t * DMODEL + d];
      const float* wr = wg + (size_t)d * NEXP;
#pragma unroll
      for (int e = 0; e < 8; ++e) acc[e] = fmaf(xv, wr[e], acc[e]);
    }
#pragma unroll
    for (int e = 0; e < 8; ++e) {
#pragma unroll
      for (int off = 32; off; off >>= 1) acc[e] += __shfl_xor(acc[e], off);
    }
    if (lane == 0) {
      float mx = acc[0];
#pragma unroll
      for (int e = 1; e < 8; ++e) mx = fmaxf(mx, acc[e]);
      float ex[8], s = 0.f;
#pragma unroll
      for (int e = 0; e < 8; ++e) { ex[e] = expf(acc[e] - mx); s += ex[e]; }
      const float inv = 1.f / s;
      float sc[8];
#pragma unroll
      for (int e = 0; e < 8; ++e) { sc[e] = ex[e] * inv; meAcc[e] += sc[e]; }
      int b0 = 0; float v0 = sc[0];
#pragma unroll
      for (int e = 1; e < 8; ++e) if (sc[e] > v0) { v0 = sc[e]; b0 = e; }
      int b1 = -1; float v1 = -1.f;
#pragma unroll
      for (int e = 0; e < 8; ++e) if (e != b0 && sc[e] > v1) { v1 = sc[e]; b1 = e; }
      idx0[t] = b0; idx1[t] = b1; g0[t] = v0; g1[t] = v1;
      ceAcc[b0] += 1;
    }
  }
  if (lane == 0) {
#pragma unroll
    for (int e = 0; e < 8; ++e) { sme[wave][e] = meAcc[e]; sce[wave][e] = ceAcc[e]; }
  }
  __syncthreads();
  if (threadIdx.x < 8) {
    const int e = threadIdx.x;
    me_part[blockIdx.x * 8 + e] = sme[0][e] + sme[1][e] + sme[2][e] + sme[3][e];
    ce_part[blockIdx.x * 8 + e] = sce[0][e] + sce[1][e] + sce[2][e] + sce[3][e];
  }
}

// ---------------------------------------------------------------------------
// 2. Exact slot-major rank scan. One block, 1024 threads, 8 chunks of 1024.
//    pos[j] = #prior same-expert assignments; slot_token inverse map.
// ---------------------------------------------------------------------------
__global__ void pos_scan_k(const int* __restrict__ idx0, const int* __restrict__ idx1,
                           int* __restrict__ pos, int* __restrict__ slot_token) {
  __shared__ int wcnt[16][8], woff[16][8], runoff[8], wtot[8];
  const int tid = threadIdx.x, wave = tid >> 6, lane = tid & 63;
  for (int i = tid; i < NEXP * CAP; i += 1024) slot_token[i] = -1;
  if (tid < 8) runoff[tid] = 0;
  __syncthreads();
  for (int chunk = 0; chunk < 8; ++chunk) {
    const int j = (chunk << 10) + tid;        // slot-major flat index
    const int t = j & (T_TOK - 1);
    const int s = j >> 12;
    const int e = s ? idx1[t] : idx0[t];
    const unsigned long long lt = (1ull << lane) - 1ull;
    int lrank = 0;
#pragma unroll
    for (int q = 0; q < 8; ++q) {
      const unsigned long long bq = __ballot(e == q);
      if (q == e) lrank = __popcll(bq & lt);
      if (lane == q) wcnt[wave][q] = __popcll(bq);
    }
    __syncthreads();
    if (tid < 8) {
      int a = 0;
      for (int w = 0; w < 16; ++w) { woff[w][tid] = a; a += wcnt[w][tid]; }
      wtot[tid] = a;
    }
    __syncthreads();
    const int p = runoff[e] + woff[wave][e] + lrank;
    pos[j] = p;
    if (p < CAP) slot_token[(e << 11) + p] = t;
    __syncthreads();
    if (tid < 8) runoff[tid] += wtot[tid];
    __syncthreads();
  }
}

// ---------------------------------------------------------------------------
// 3. l_aux = E * sum_e (me_e/T)*(ce_e/T) -> d_out[T*D]
// ---------------------------------------------------------------------------
__global__ void laux_k(const float* __restrict__ me_part, const int* __restrict__ ce_part,
                       float* __restrict__ out_laux) {
  __shared__ float sm[8]; __shared__ int sc[8];
  if (threadIdx.x < 8) {
    float m = 0.f; int c = 0;
    for (int b = 0; b < 64; ++b) { m += me_part[b * 8 + threadIdx.x]; c += ce_part[b * 8 + threadIdx.x]; }
    sm[threadIdx.x] = m; sc[threadIdx.x] = c;
  }
  __syncthreads();
  if (threadIdx.x == 0) {
    float s = 0.f;
    for (int e = 0; e < 8; ++e)
      s += (sm[e] / (float)T_TOK) * ((float)sc[e] / (float)T_TOK);
    out_laux[0] = (float)NEXP * s;
  }
}

// ---------------------------------------------------------------------------
// 4. Dispatch: gather x rows -> bf16 dispatched [E][CAP][D]; zero empty rows.
//    Grid: E*CAP blocks x 256 thr (8 bf16 per thread).
// ---------------------------------------------------------------------------
__global__ __launch_bounds__(256) void dispatch_k(
    const float* __restrict__ x, const int* __restrict__ slot_token,
    u16* __restrict__ disp) {
  const int row = blockIdx.x;
  const int tok = slot_token[row];
  const int tid = threadIdx.x;
  union { uint4 v; u16 u[8]; } pk;
  if (tok >= 0) {
    const float4* xr = (const float4*)(x + (size_t)tok * DMODEL) + tid * 2;
    const float4 a = xr[0], b = xr[1];
    pk.u[0] = f2bf(a.x); pk.u[1] = f2bf(a.y); pk.u[2] = f2bf(a.z); pk.u[3] = f2bf(a.w);
    pk.u[4] = f2bf(b.x); pk.u[5] = f2bf(b.y); pk.u[6] = f2bf(b.z); pk.u[7] = f2bf(b.w);
  } else {
    pk.v = make_uint4(0, 0, 0, 0);
  }
  ((uint4*)(disp + (size_t)row * DMODEL))[tid] = pk.v;
}

// ---------------------------------------------------------------------------
// 5. Weight convert+transpose: fp32 [K][N] -> bf16 [N][K]. 64x64 tiles.
// ---------------------------------------------------------------------------
__global__ __launch_bounds__(256) void convert_wT(
    const float* __restrict__ src, u16* __restrict__ dst,
    int K, int N, long srcE, long dstE) {
  __shared__ float ld[64][65];
  const int e = blockIdx.z;
  src += (size_t)e * srcE; dst += (size_t)e * dstE;
  const int k0 = blockIdx.x * 64, n0 = blockIdx.y * 64;
  const int tid = threadIdx.x;
  const int c = tid & 63, r0 = tid >> 6;
#pragma unroll
  for (int i = 0; i < 16; ++i) {
    const int kr = r0 + (i << 2);
    ld[kr][c] = src[(size_t)(k0 + kr) * N + n0 + c];
  }
  __syncthreads();
#pragma unroll
  for (int it = 0; it < 2; ++it) {
    const int item = tid + it * 256;
    const int nl = item >> 3, kl = (item & 7) * 8;
    union { uint4 v; u16 u[8]; } pk;
#pragma unroll
    for (int jj = 0; jj < 8; ++jj) pk.u[jj] = f2bf(ld[kl + jj][nl]);
    *(uint4*)&dst[(size_t)(n0 + nl) * K + k0 + kl] = pk.v;
  }
}

// ---------------------------------------------------------------------------
// 6. GEMM (m97 structure): C[M][N] = A[M][K] @ BT[N][K]^T + bias, opt ReLU.
//    128x128 tile, BK=32, 4 waves, 4x4 16x16x32 bf16 MFMA frags per wave,
//    global_load_lds width-16 staging, unpadded LDS.
// ---------------------------------------------------------------------------
template <bool RELU>
__global__ __launch_bounds__(256) void gemm_bt(
    const u16* __restrict__ A, const u16* __restrict__ BT,
    const float* __restrict__ bias, u16* __restrict__ C,
    int N, int K, long aE, long bE, long biasE, long cE) {
  const int e = blockIdx.z;
  A += (size_t)e * aE; BT += (size_t)e * bE;
  bias += (size_t)e * biasE; C += (size_t)e * cE;

  __shared__ __align__(16) u16 As[128 * 32];
  __shared__ __align__(16) u16 Bs[128 * 32];

  const int tid = threadIdx.x, lane = tid & 63, wave = tid >> 6;
  const int m0 = blockIdx.y * 128, n0 = blockIdx.x * 128;
  const int wm = (wave >> 1) * 64, wn = (wave & 1) * 64;
  const int q8 = (lane >> 4) * 8;     // k-offset of this lane's quad
  const int l15 = lane & 15;

  f32x4 acc[4][4];
#pragma unroll
  for (int i = 0; i < 4; ++i)
#pragma unroll
    for (int j = 0; j < 4; ++j) acc[i][j] = (f32x4){0.f, 0.f, 0.f, 0.f};

  u16* Anc = const_cast<u16*>(A);
  u16* Bnc = const_cast<u16*>(BT);

  for (int kb = 0; kb < K; kb += 32) {
    __syncthreads();
#pragma unroll
    for (int it = 0; it < 2; ++it) {
      const int chunk = it * 256 + wave * 64 + lane;   // 16B chunks
      const int row = chunk >> 2, kc = (chunk & 3) * 8;
      u16* ga = Anc + (size_t)(m0 + row) * K + kb + kc;
      u16* gb = Bnc + (size_t)(n0 + row) * K + kb + kc;
      // LDS dest = wave-uniform base + lane*16
      __builtin_amdgcn_global_load_lds(
          (__attribute__((address_space(1))) void*)ga,
          (__attribute__((address_space(3))) void*)(As + (size_t)(it * 256 + wave * 64) * 8),
          16, 0, 0);
      __builtin_amdgcn_global_load_lds(
          (__attribute__((address_space(1))) void*)gb,
          (__attribute__((address_space(3))) void*)(Bs + (size_t)(it * 256 + wave * 64) * 8),
          16, 0, 0);
    }
    __syncthreads();   // drains vmcnt for global_load_lds

    short8 af[4], bfr[4];
#pragma unroll
    for (int i = 0; i < 4; ++i)
      af[i] = *(const short8*)&As[(wm + i * 16 + l15) * 32 + q8];
#pragma unroll
    for (int j = 0; j < 4; ++j)
      bfr[j] = *(const short8*)&Bs[(wn + j * 16 + l15) * 32 + q8];
#pragma unroll
    for (int i = 0; i < 4; ++i)
#pragma unroll
      for (int j = 0; j < 4; ++j)
        acc[i][j] = __builtin_amdgcn_mfma_f32_16x16x32_bf16(af[i], bfr[j], acc[i][j], 0, 0, 0);
  }

  // epilogue: C/D layout col=lane&15, row=(lane>>4)*4+reg
#pragma unroll
  for (int j = 0; j < 4; ++j) {
    const int col = n0 + wn + j * 16 + l15;
    const float bj = bias[col];
#pragma unroll
    for (int i = 0; i < 4; ++i) {
      const int rbase = m0 + wm + i * 16 + (lane >> 4) * 4;
#pragma unroll
      for (int r = 0; r < 4; ++r) {
        float v = acc[i][j][r] + bj;
        if (RELU) v = fmaxf(v, 0.f);
        C[(size_t)(rbase + r) * N + col] = f2bf(v);
      }
    }
  }
}

// ---------------------------------------------------------------------------
// 7. Decode: out[t] = keep0*g0*y[e0,p0] + keep1*g1*y[e1,p1]. Grid: T x 256.
// ---------------------------------------------------------------------------
__global__ __launch_bounds__(256) void decode_k(
    const u16* __restrict__ y, const int* __restrict__ idx0, const int* __restrict__ idx1,
    const float* __restrict__ g0, const float* __restrict__ g1,
    const int* __restrict__ pos, float* __restrict__ out) {
  const int t = blockIdx.x, tid = threadIdx.x;
  const int e0 = idx0[t], e1 = idx1[t];
  int p0 = pos[t], p1 = pos[T_TOK + t];
  float w0 = 0.f, w1 = 0.f;
  if (p0 < CAP) w0 = g0[t]; else p0 = 0;
  if (p1 < CAP) w1 = g1[t]; else p1 = 0;
  const uint4* r0 = (const uint4*)(y + ((size_t)e0 * CAP + p0) * DMODEL);
  const uint4* r1 = (const uint4*)(y + ((size_t)e1 * CAP + p1) * DMODEL);
  union { uint4 v; u16 u[8]; } a, b;
  a.v = r0[tid]; b.v = r1[tid];
  float o[8];
#pragma unroll
  for (int i = 0; i < 8; ++i) o[i] = w0 * bf2f(a.u[i]) + w1 * bf2f(b.u[i]);
  float4* dst = (float4*)(out + (size_t)t * DMODEL) + tid * 2;
  dst[0] = make_float4(o[0], o[1], o[2], o[3]);
  dst[1] = make_float4(o[4], o[5], o[6], o[7]);
}

// ---------------------------------------------------------------------------
extern "C" void kernel_launch(void* const* d_in, const int* in_sizes, int n_in,
                              void* d_out, int out_size, void* d_ws, size_t ws_size,
                              hipStream_t stream) {
  const float* x  = (const float*)d_in[0];
  const float* wg = (const float*)d_in[1];
  const float* w1 = (const float*)d_in[2];
  const float* b1 = (const float*)d_in[3];
  const float* w2 = (const float*)d_in[4];
  const float* b2 = (const float*)d_in[5];
  float* out = (float*)d_out;

  char* ws = (char*)d_ws;
  size_t off = 0;
  auto alloc = [&](size_t n) -> char* {
    char* p = ws + off;
    off += (n + 255) & ~(size_t)255;
    return p;
  };

  int*   idx0 = (int*)alloc(T_TOK * 4);
  int*   idx1 = (int*)alloc(T_TOK * 4);
  float* g0   = (float*)alloc(T_TOK * 4);
  float* g1   = (float*)alloc(T_TOK * 4);
  int*   pos  = (int*)alloc(2 * T_TOK * 4);
  int*   slot = (int*)alloc(NEXP * CAP * 4);
  float* mep  = (float*)alloc(64 * 8 * 4);
  int*   cep  = (int*)alloc(64 * 8 * 4);

  u16* disp = (u16*)alloc((size_t)NEXP * CAP * DMODEL * 2);   // 67 MB
  u16* yv   = (u16*)alloc((size_t)NEXP * CAP * DMODEL * 2);   // 67 MB

  const size_t wBytes = (size_t)NEXP * DMODEL * HDIM * 2;     // 268 MB each
  const size_t hBytes = (size_t)NEXP * CAP * HDIM * 2;        // 268 MB
  const bool tierA = (ws_size >= off + 2 * wBytes + hBytes + 1024);

  // common front-end
  routing_k<<<dim3(64), dim3(256), 0, stream>>>(x, wg, idx0, idx1, g0, g1, mep, cep);
  pos_scan_k<<<dim3(1), dim3(1024), 0, stream>>>(idx0, idx1, pos, slot);
  laux_k<<<dim3(1), dim3(64), 0, stream>>>(mep, cep, out + (size_t)T_TOK * DMODEL);
  dispatch_k<<<dim3(NEXP * CAP), dim3(256), 0, stream>>>(x, slot, disp);

  if (tierA) {
    u16* W1T = (u16*)alloc(wBytes);   // [E][H][D]
    u16* W2T = (u16*)alloc(wBytes);   // [E][D][H]
    u16* h   = (u16*)alloc(hBytes);   // [E][CAP][H]
    convert_wT<<<dim3(DMODEL / 64, HDIM / 64, NEXP), dim3(256), 0, stream>>>(
        w1, W1T, DMODEL, HDIM, (long)DMODEL * HDIM, (long)DMODEL * HDIM);
    convert_wT<<<dim3(HDIM / 64, DMODEL / 64, NEXP), dim3(256), 0, stream>>>(
        w2, W2T, HDIM, DMODEL, (long)HDIM * DMODEL, (long)HDIM * DMODEL);
    gemm_bt<true><<<dim3(HDIM / 128, CAP / 128, NEXP), dim3(256), 0, stream>>>(
        disp, W1T, b1, h, HDIM, DMODEL,
        (long)CAP * DMODEL, (long)HDIM * DMODEL, (long)HDIM, (long)CAP * HDIM);
    gemm_bt<false><<<dim3(DMODEL / 128, CAP / 128, NEXP), dim3(256), 0, stream>>>(
        h, W2T, b2, yv, DMODEL, HDIM,
        (long)CAP * HDIM, (long)DMODEL * HDIM, (long)DMODEL, (long)CAP * DMODEL);
  } else {
    // per-expert fallback (~235 MB workspace)
    u16* W1Tb = (u16*)alloc((size_t)DMODEL * HDIM * 2);
    u16* W2Tb = (u16*)alloc((size_t)DMODEL * HDIM * 2);
    u16* hb   = (u16*)alloc((size_t)CAP * HDIM * 2);
    for (int e = 0; e < NEXP; ++e) {
      convert_wT<<<dim3(DMODEL / 64, HDIM / 64, 1), dim3(256), 0, stream>>>(
          w1 + (size_t)e * DMODEL * HDIM, W1Tb, DMODEL, HDIM, 0, 0);
      convert_wT<<<dim3(HDIM / 64, DMODEL / 64, 1), dim3(256), 0, stream>>>(
          w2 + (size_t)e * HDIM * DMODEL, W2Tb, HDIM, DMODEL, 0, 0);
      gemm_bt<true><<<dim3(HDIM / 128, CAP / 128, 1), dim3(256), 0, stream>>>(
          disp + (size_t)e * CAP * DMODEL, W1Tb, b1 + (size_t)e * HDIM, hb,
          HDIM, DMODEL, 0, 0, 0, 0);
      gemm_bt<false><<<dim3(DMODEL / 128, CAP / 128, 1), dim3(256), 0, stream>>>(
          hb, W2Tb, b2 + (size_t)e * DMODEL, yv + (size_t)e * CAP * DMODEL,
          DMODEL, HDIM, 0, 0, 0, 0);
    }
  }

  decode_k<<<dim3(T_TOK), dim3(256), 0, stream>>>(yv, idx0, idx1, g0, g1, pos, out);
}